// Round 1
// baseline (195.845 us; speedup 1.0000x reference)
//
#include <hip/hip_runtime.h>
#include <stdint.h>

// YOLO loss R7: global_load_lds (direct HBM->LDS DMA) + double-buffered LDS
// + counted s_waitcnt vmcnt(25) -- never drain to 0 in the main loop.
// Theory: R2..R6's ~2.7 TB/s pin is the per-tile burst{15 loads} ->
// drain{vmcnt countdown + 15 ds_writes} -> consume serial chain of the
// VGPR round-trip; gld_lds removes the round-trip entirely and keeps one
// full buffer (25 loads) in flight at all times. Sizes restricted to
// HW-measured 16B and 4B (m97/m03). LDS layout stays linear, so compute
// is identical to the verified R6 layout.
// Predict: main 66us -> ~40us, bench dur 180.6 -> ~155. If unchanged,
// per-CU outstanding-request-cap theory wins; pivot to wider request spread.

#define NCLS   20
#define SLOTS  128
#define GRID   1280          // 5 blocks/CU x 256 CU (LDS-bound: 28,160 B/block)
#define TILES  12544         // 802816 cells / 64 cells per tile
#define PRED_F 1920          // floats per pred tile (64 cells x 30)
#define TGT_F  1600          // floats per target tile (64 cells x 25)

// ---- direct global->LDS staging (LDS dest = uniform base + lane*size) ----
__device__ static inline void gl16(const float* g, float* l) {
    __builtin_amdgcn_global_load_lds(
        (const __attribute__((address_space(1))) void*)g,
        (__attribute__((address_space(3))) void*)l, 16, 0, 0);
}
__device__ static inline void gl4(const float* g, float* l) {
    __builtin_amdgcn_global_load_lds(
        (const __attribute__((address_space(1))) void*)g,
        (__attribute__((address_space(3))) void*)l, 4, 0, 0);
}

// 25 full-wave load instrs per tile (the vmcnt unit):
//   pred 7680B = 6 x 1024B (16B/lane) + 6 x 256B (4B/lane)
//   tgt  6400B = 4 x 1024B (16B/lane) + 9 x 256B (4B/lane)
__device__ static inline void stage_tile(const float* __restrict__ pred,
                                         const float* __restrict__ target,
                                         int tile, float* sp, float* st,
                                         int lane)
{
    const float* gp = pred   + (size_t)tile * PRED_F;
    const float* gt = target + (size_t)tile * TGT_F;
    #pragma unroll
    for (int c = 0; c < 6; ++c) gl16(gp + c * 256 + lane * 4, sp + c * 256);
    #pragma unroll
    for (int c = 0; c < 6; ++c) gl4 (gp + 1536 + c * 64 + lane, sp + 1536 + c * 64);
    #pragma unroll
    for (int c = 0; c < 4; ++c) gl16(gt + c * 256 + lane * 4, st + c * 256);
    #pragma unroll
    for (int c = 0; c < 9; ++c) gl4 (gt + 1024 + c * 64 + lane, st + 1024 + c * 64);
}

__global__ __launch_bounds__(64) void yolo_main(
    const float* __restrict__ pred,
    const float* __restrict__ target,
    float* __restrict__ ws)
{
    __shared__ float sp0[PRED_F], st0[TGT_F];   // buffer 0: 14,080 B
    __shared__ float sp1[PRED_F], st1[TGT_F];   // buffer 1: 14,080 B

    const int lane = threadIdx.x;
    const int blk  = blockIdx.x;
    const int n = (TILES - blk + GRID - 1) / GRID;   // 10 (blk<1024) or 9

    const float EPS = 1e-6f;

    // prologue: fill both buffers (50 loads in flight)
    stage_tile(pred, target, blk, sp0, st0, lane);
    if (n > 1) stage_tile(pred, target, blk + GRID, sp1, st1, lane);

    float acc = 0.0f;

    for (int i = 0; i < n; ++i) {
        if (i + 1 < n) {
            // current buffer landed; next buffer's 25 loads stay in flight
            asm volatile("s_waitcnt vmcnt(25)" ::: "memory");
        } else {
            asm volatile("s_waitcnt vmcnt(0)" ::: "memory");
        }
        __builtin_amdgcn_sched_barrier(0);

        const float* lp = ((i & 1) ? sp1 : sp0) + lane * 30;
        const float* lt = ((i & 1) ? st1 : st0) + lane * 25;

        const float tobj = lt[20];
        const float tx = lt[21], ty = lt[22], tw = lt[23], th = lt[24];

        const float t_x1 = tx - tw * 0.5f, t_x2 = tx + tw * 0.5f;
        const float t_y1 = ty - th * 0.5f, t_y2 = ty + th * 0.5f;
        const float t_area = fabsf((t_x2 - t_x1) * (t_y2 - t_y1));

        float iou[2];
        #pragma unroll
        for (int b = 0; b < 2; ++b) {
            const float bx = lp[NCLS + 5 * b + 1];
            const float by = lp[NCLS + 5 * b + 2];
            const float bw = lp[NCLS + 5 * b + 3];
            const float bh = lp[NCLS + 5 * b + 4];
            const float x1 = bx - bw * 0.5f, x2 = bx + bw * 0.5f;
            const float y1 = by - bh * 0.5f, y2 = by + bh * 0.5f;
            const float iw = fmaxf(fminf(x2, t_x2) - fmaxf(x1, t_x1), 0.0f);
            const float ih = fmaxf(fminf(y2, t_y2) - fmaxf(y1, t_y1), 0.0f);
            const float inter = iw * ih;
            const float a1 = fabsf((x2 - x1) * (y2 - y1));
            iou[b] = inter / (a1 + t_area - inter + EPS);
        }
        const int best = (iou[1] > iou[0]) ? 1 : 0;

        const float bconf = lp[NCLS + 5 * best + 0];
        const float bxv   = lp[NCLS + 5 * best + 1];
        const float byv   = lp[NCLS + 5 * best + 2];
        const float bwv   = lp[NCLS + 5 * best + 3];
        const float bhv   = lp[NCLS + 5 * best + 4];

        const float sgnw = (bwv > 0.f) ? 1.f : ((bwv < 0.f) ? -1.f : 0.f);
        const float sgnh = (bhv > 0.f) ? 1.f : ((bhv < 0.f) ? -1.f : 0.f);
        const float swv = sgnw * sqrtf(fabsf(bwv) + EPS);
        const float shv = sgnh * sqrtf(fabsf(bhv) + EPS);

        float d0 = tobj * bxv - tobj * tx;
        float d1 = tobj * byv - tobj * ty;
        float d2 = tobj * swv - sqrtf(fmaxf(tobj * tw, 0.0f));
        float d3 = tobj * shv - sqrtf(fmaxf(tobj * th, 0.0f));
        float box_loss = d0 * d0 + d1 * d1 + d2 * d2 + d3 * d3;

        const float noobj = 1.0f - tobj;
        float n0 = noobj * (lp[NCLS + 0] - tobj);
        float n1 = noobj * (lp[NCLS + 5] - tobj);
        float no_object_loss = n0 * n0 + n1 * n1;

        float od = tobj * (bconf - tobj);
        float object_loss = od * od;

        float class_loss = 0.0f;
        #pragma unroll
        for (int k = 0; k < NCLS; ++k) {
            float cd = tobj * (lp[k] - lt[k]);
            class_loss += cd * cd;
        }

        acc += 5.0f * box_loss + object_loss + 0.5f * no_object_loss + class_loss;

        // refill the buffer we just consumed with tile i+2
        if (i + 2 < n) {
            // make sure our ds_reads have sampled LDS before DMA overwrites it
            asm volatile("s_waitcnt lgkmcnt(0)" ::: "memory");
            __builtin_amdgcn_sched_barrier(0);
            stage_tile(pred, target, blk + (i + 2) * GRID,
                       (i & 1) ? sp1 : sp0, (i & 1) ? st1 : st0, lane);
        }
    }

    // wave reduce + one spread atomic per wave
    #pragma unroll
    for (int off = 32; off > 0; off >>= 1)
        acc += __shfl_down(acc, off, 64);

    if (lane == 0)
        atomicAdd(&ws[blk & (SLOTS - 1)], acc);
}

__global__ __launch_bounds__(64) void yolo_reduce(
    const float* __restrict__ ws, float* __restrict__ out)
{
    const int lane = threadIdx.x;
    float s = ws[lane] + ws[lane + 64];
    #pragma unroll
    for (int off = 32; off > 0; off >>= 1)
        s += __shfl_down(s, off, 64);
    if (lane == 0) out[0] = s;
}

extern "C" void kernel_launch(void* const* d_in, const int* in_sizes, int n_in,
                              void* d_out, int out_size, void* d_ws, size_t ws_size,
                              hipStream_t stream) {
    const float* pred   = (const float*)d_in[0];
    const float* target = (const float*)d_in[1];
    float* ws  = (float*)d_ws;
    float* out = (float*)d_out;

    hipMemsetAsync(ws, 0, SLOTS * sizeof(float), stream);

    hipLaunchKernelGGL(yolo_main, dim3(GRID), dim3(64), 0, stream,
                       pred, target, ws);
    hipLaunchKernelGGL(yolo_reduce, dim3(1), dim3(64), 0, stream, ws, out);
}

// Round 2
// 182.033 us; speedup vs baseline: 1.0759x; 1.0759x over previous
//
#include <hip/hip_runtime.h>
#include <stdint.h>

// YOLO loss R8: NT register staging (R6's proven -15us ingredient) +
// double register buffer so 15 NT loads (14KB/wave) stay in flight through
// every drain+compute phase (kills R5/R6's burst->drain-to-zero cycle).
// Per-dispatch history: R5 (no NT, 1-deep) 66us; R6 (NT, 1-deep) <=56us
// (masked by fills; ~50us inferred); R7 (DMA, no NT, counted vmcnt) 65.7us.
// -> NT is worth ~15us; concurrency depth untested at constant NT. This
// round isolates depth WITH NT held.
// Predict: main ~38-45us (4.2-4.6 TB/s delivered). If ~50us -> depth is
// not the limiter; pivot to cache-policy sweep (sc0/sc1/nt aux variants).

#define NCLS   20
#define SLOTS  128
#define GRID   2048          // 8 blocks/CU x 256 CU (VGPR-bound cohort)
#define TILES  12544         // 802816 cells / 64 cells per tile
#define PRED_F 1920          // floats per pred tile (64 cells x 30)
#define TGT_F  1600          // floats per target tile (64 cells x 25)

typedef float f4 __attribute__((ext_vector_type(4)));  // 16B aligned

__device__ static inline f4 ldg4nt(const float* p) {
    return __builtin_nontemporal_load((const f4*)p);
}

struct Tile {
    f4 rp[8];   // pred: 7 full-wave 1024B chunks + 1 half-wave (lane<32)
    f4 rt[7];   // tgt : 6 full-wave 1024B chunks + 1 quarter-wave (lane<16)
};

__device__ static inline void load_tile(Tile& T,
                                        const float* __restrict__ pred,
                                        const float* __restrict__ target,
                                        int tile, int lane)
{
    const float* gp = pred   + (size_t)tile * PRED_F;
    const float* gt = target + (size_t)tile * TGT_F;
    #pragma unroll
    for (int c = 0; c < 7; ++c) T.rp[c] = ldg4nt(gp + lane * 4 + c * 256);
    if (lane < 32) T.rp[7] = ldg4nt(gp + lane * 4 + 7 * 256);
    #pragma unroll
    for (int c = 0; c < 6; ++c) T.rt[c] = ldg4nt(gt + lane * 4 + c * 256);
    if (lane < 16) T.rt[6] = ldg4nt(gt + lane * 4 + 6 * 256);
}

__device__ static inline void drain_tile(const Tile& T, float* sp, float* st,
                                         int lane)
{
    #pragma unroll
    for (int c = 0; c < 7; ++c) *(f4*)(sp + lane * 4 + c * 256) = T.rp[c];
    if (lane < 32) *(f4*)(sp + lane * 4 + 7 * 256) = T.rp[7];
    #pragma unroll
    for (int c = 0; c < 6; ++c) *(f4*)(st + lane * 4 + c * 256) = T.rt[c];
    if (lane < 16) *(f4*)(st + lane * 4 + 6 * 256) = T.rt[6];
}

__device__ static inline float compute_cell(const float* lp, const float* lt)
{
    const float EPS = 1e-6f;

    const float tobj = lt[20];
    const float tx = lt[21], ty = lt[22], tw = lt[23], th = lt[24];

    const float t_x1 = tx - tw * 0.5f, t_x2 = tx + tw * 0.5f;
    const float t_y1 = ty - th * 0.5f, t_y2 = ty + th * 0.5f;
    const float t_area = fabsf((t_x2 - t_x1) * (t_y2 - t_y1));

    float iou[2];
    #pragma unroll
    for (int b = 0; b < 2; ++b) {
        const float bx = lp[NCLS + 5 * b + 1];
        const float by = lp[NCLS + 5 * b + 2];
        const float bw = lp[NCLS + 5 * b + 3];
        const float bh = lp[NCLS + 5 * b + 4];
        const float x1 = bx - bw * 0.5f, x2 = bx + bw * 0.5f;
        const float y1 = by - bh * 0.5f, y2 = by + bh * 0.5f;
        const float iw = fmaxf(fminf(x2, t_x2) - fmaxf(x1, t_x1), 0.0f);
        const float ih = fmaxf(fminf(y2, t_y2) - fmaxf(y1, t_y1), 0.0f);
        const float inter = iw * ih;
        const float a1 = fabsf((x2 - x1) * (y2 - y1));
        iou[b] = inter / (a1 + t_area - inter + EPS);
    }
    const int best = (iou[1] > iou[0]) ? 1 : 0;

    const float bconf = lp[NCLS + 5 * best + 0];
    const float bxv   = lp[NCLS + 5 * best + 1];
    const float byv   = lp[NCLS + 5 * best + 2];
    const float bwv   = lp[NCLS + 5 * best + 3];
    const float bhv   = lp[NCLS + 5 * best + 4];

    const float sgnw = (bwv > 0.f) ? 1.f : ((bwv < 0.f) ? -1.f : 0.f);
    const float sgnh = (bhv > 0.f) ? 1.f : ((bhv < 0.f) ? -1.f : 0.f);
    const float swv = sgnw * sqrtf(fabsf(bwv) + EPS);
    const float shv = sgnh * sqrtf(fabsf(bhv) + EPS);

    float d0 = tobj * bxv - tobj * tx;
    float d1 = tobj * byv - tobj * ty;
    float d2 = tobj * swv - sqrtf(fmaxf(tobj * tw, 0.0f));
    float d3 = tobj * shv - sqrtf(fmaxf(tobj * th, 0.0f));
    float box_loss = d0 * d0 + d1 * d1 + d2 * d2 + d3 * d3;

    const float noobj = 1.0f - tobj;
    float n0 = noobj * (lp[NCLS + 0] - tobj);
    float n1 = noobj * (lp[NCLS + 5] - tobj);
    float no_object_loss = n0 * n0 + n1 * n1;

    float od = tobj * (bconf - tobj);
    float object_loss = od * od;

    float class_loss = 0.0f;
    #pragma unroll
    for (int k = 0; k < NCLS; ++k) {
        float cd = tobj * (lp[k] - lt[k]);
        class_loss += cd * cd;
    }

    return 5.0f * box_loss + object_loss + 0.5f * no_object_loss + class_loss;
}

__global__ __launch_bounds__(64, 2) void yolo_main(
    const float* __restrict__ pred,
    const float* __restrict__ target,
    float* __restrict__ ws)
{
    __shared__ float sp[PRED_F];   // 7,680 B
    __shared__ float st[TGT_F];    // 6,400 B

    const int lane = threadIdx.x;
    const int blk  = blockIdx.x;
    const int n = (TILES - blk + GRID - 1) / GRID;   // 7 (blk<256) or 6

    Tile A, B;                      // 2 x 15 f4 = 120 VGPRs of staging
    load_tile(A, pred, target, blk, lane);

    float acc = 0.0f;
    int i = 0;

    while (true) {
        // ---- A holds tile i; issue tile i+1 into B BEFORE draining A.
        //      Drain's waits become vmcnt(29..15): B's 14KB stays in flight
        //      through the whole drain+compute phase.
        if (i + 1 < n) load_tile(B, pred, target, blk + (i + 1) * GRID, lane);
        __builtin_amdgcn_sched_barrier(0);   // pin load issue before drain
        drain_tile(A, sp, st, lane);
        acc += compute_cell(sp + lane * 30, st + lane * 25);
        __asm__ volatile("" ::: "memory");   // keep LDS reads inside this iter
        if (++i >= n) break;

        // ---- B holds tile i; mirror phase.
        if (i + 1 < n) load_tile(A, pred, target, blk + (i + 1) * GRID, lane);
        __builtin_amdgcn_sched_barrier(0);
        drain_tile(B, sp, st, lane);
        acc += compute_cell(sp + lane * 30, st + lane * 25);
        __asm__ volatile("" ::: "memory");
        if (++i >= n) break;
    }

    // wave reduce + one spread atomic per wave
    #pragma unroll
    for (int off = 32; off > 0; off >>= 1)
        acc += __shfl_down(acc, off, 64);

    if (lane == 0)
        atomicAdd(&ws[blk & (SLOTS - 1)], acc);
}

__global__ __launch_bounds__(64) void yolo_reduce(
    const float* __restrict__ ws, float* __restrict__ out)
{
    const int lane = threadIdx.x;
    float s = ws[lane] + ws[lane + 64];
    #pragma unroll
    for (int off = 32; off > 0; off >>= 1)
        s += __shfl_down(s, off, 64);
    if (lane == 0) out[0] = s;
}

extern "C" void kernel_launch(void* const* d_in, const int* in_sizes, int n_in,
                              void* d_out, int out_size, void* d_ws, size_t ws_size,
                              hipStream_t stream) {
    const float* pred   = (const float*)d_in[0];
    const float* target = (const float*)d_in[1];
    float* ws  = (float*)d_ws;
    float* out = (float*)d_out;

    hipMemsetAsync(ws, 0, SLOTS * sizeof(float), stream);

    hipLaunchKernelGGL(yolo_main, dim3(GRID), dim3(64), 0, stream,
                       pred, target, ws);
    hipLaunchKernelGGL(yolo_reduce, dim3(1), dim3(64), 0, stream, ws, out);
}